// Round 5
// baseline (173.445 us; speedup 1.0000x reference)
//
#include <hip/hip_runtime.h>

typedef __bf16 bf16_t;
typedef __bf16 bf16x2 __attribute__((ext_vector_type(2)));
typedef __bf16 bf16x8 __attribute__((ext_vector_type(8)));
typedef float  f32x4  __attribute__((ext_vector_type(4)));
typedef float  f32x16 __attribute__((ext_vector_type(16)));
typedef unsigned u32x4 __attribute__((ext_vector_type(4)));

#define HIN 128
#define WIN 128
#define LOG2E 1.4426950408889634f

__device__ __forceinline__ unsigned pk(float a, float b) {
    bf16x2 v; v[0] = (bf16_t)a; v[1] = (bf16_t)b;
    return __builtin_bit_cast(unsigned, v);
}

__device__ __forceinline__ void glds16(const bf16_t* g, bf16_t* l) {
    __builtin_amdgcn_global_load_lds(
        (const __attribute__((address_space(1))) unsigned int*)g,
        (__attribute__((address_space(3))) unsigned int*)l, 16, 0, 0);
}

// pi: self-inverse swap of bits 2,3 within a 16-key block (V column permutation)
__device__ __forceinline__ int vperm16(int p) {
    return (p & 3) | (((p >> 3) & 1) << 2) | (((p >> 2) & 1) << 3);
}

// ---------------------------------------------------------------------------
// Kernel 1: space-to-depth gather + Q/K/V projections via bf16 MFMA 16x16x32.
// Weights converted fp32->bf16 inline (L2/L3-hot). grid 512 = (b, h2, half).
// Q,K: [b][n][32] bf16 ; V: [b][c][n] bf16 with per-16-block column perm pi.
// ---------------------------------------------------------------------------
__global__ __launch_bounds__(256) void proj_kernel(
    const float* __restrict__ x,
    const float* __restrict__ wq, const float* __restrict__ bq,
    const float* __restrict__ wk, const float* __restrict__ bk,
    const float* __restrict__ wv, const float* __restrict__ bv,
    bf16_t* __restrict__ Qg, bf16_t* __restrict__ Kg, bf16_t* __restrict__ Vg)
{
    __shared__ __attribute__((aligned(16))) bf16_t Xs[32 * 256]; // 16KB
    __shared__ bf16_t Ls[320 * 34];                              // 21.25KB, padded
    const int blk  = blockIdx.x;
    const int half = blk & 1;
    const int h2   = (blk >> 1) & 63;
    const int b    = blk >> 7;
    const int tid  = threadIdx.x;

    const float* xb = x + ((size_t)b << 20);
    for (int s = 0; s < 8; ++s) {
        int v   = tid + (s << 8);     // 0..2047 float4 units
        int cin = v >> 5;             // 0..63
        int hb  = (v >> 4) & 1;
        int w4l = v & 15;
        const float4 xv = *(const float4*)(xb + ((size_t)cin * HIN + (2*h2 + hb)) * WIN
                                           + ((half * 16 + w4l) << 2));
        float vals[4] = {xv.x, xv.y, xv.z, xv.w};
        #pragma unroll
        for (int j = 0; j < 4; ++j) {
            int nl = ((w4l << 2) + j) >> 1;
            int c  = ((j & 1) << 7) + (hb << 6) + cin;
            int chunk = c >> 3;
            int phys  = chunk ^ (nl & 7);
            Xs[(nl << 8) + (phys << 3) + (c & 7)] = (bf16_t)vals[j];
        }
    }
    __syncthreads();

    const int ln = tid & 63;
    const int w  = tid >> 6;
    const int l  = ln & 15;
    const int q  = ln >> 4;

    const float* wrow[5];
    int row_o[5];
    f32x4 acc[5][2];
    #pragma unroll
    for (int i = 0; i < 5; ++i) {
        int ot = w * 5 + i;
        int o  = ot * 16 + l;
        row_o[i] = o;
        float bias;
        if (ot < 2)      { wrow[i] = wq + (size_t)o * 256;        bias = bq[o]; }
        else if (ot < 4) { wrow[i] = wk + (size_t)(o - 32) * 256; bias = bk[o - 32]; }
        else             { wrow[i] = wv + (size_t)(o - 64) * 256; bias = bv[o - 64]; }
        #pragma unroll
        for (int nt = 0; nt < 2; ++nt) {
            acc[i][nt][0] = bias; acc[i][nt][1] = bias;
            acc[i][nt][2] = bias; acc[i][nt][3] = bias;
        }
    }

    for (int ks = 0; ks < 8; ++ks) {
        bf16x8 a[2];
        #pragma unroll
        for (int nt = 0; nt < 2; ++nt) {
            int phys = ((ks << 2) + q) ^ (l & 7);
            a[nt] = *(const bf16x8*)&Xs[((nt * 16 + l) << 8) + (phys << 3)];
        }
        #pragma unroll
        for (int i = 0; i < 5; ++i) {
            const float* wp = wrow[i] + (ks << 5) + (q << 3);
            float4 w0 = *(const float4*)wp;
            float4 w1 = *(const float4*)(wp + 4);
            bf16x8 bw = { (bf16_t)w0.x, (bf16_t)w0.y, (bf16_t)w0.z, (bf16_t)w0.w,
                          (bf16_t)w1.x, (bf16_t)w1.y, (bf16_t)w1.z, (bf16_t)w1.w };
            #pragma unroll
            for (int nt = 0; nt < 2; ++nt)
                acc[i][nt] = __builtin_amdgcn_mfma_f32_16x16x32_bf16(a[nt], bw, acc[i][nt], 0, 0, 0);
        }
    }

    // transpose-stage results: Ls[o][nl], stride 34 (odd dwords -> no conflicts)
    #pragma unroll
    for (int i = 0; i < 5; ++i)
        #pragma unroll
        for (int nt = 0; nt < 2; ++nt)
            #pragma unroll
            for (int reg = 0; reg < 4; ++reg)
                Ls[row_o[i] * 34 + nt * 16 + q * 4 + reg] = (bf16_t)acc[i][nt][reg];
    __syncthreads();

    const int nbase = h2 * 64 + half * 32;
    // Q and K: [n][32] rows, each 64B = 4 x b128
    {
        int task = tid >> 7;          // 0 = Q, 1 = K
        int v    = tid & 127;
        int n    = v >> 2, part = v & 3;
        bf16x8 pkv;
        #pragma unroll
        for (int j = 0; j < 8; ++j)
            pkv[j] = Ls[(task * 32 + part * 8 + j) * 34 + n];
        bf16_t* dst = task ? Kg : Qg;
        *(bf16x8*)(dst + (((size_t)(b * 4096 + nbase + n)) << 5) + part * 8) = pkv;
    }
    // V: 256 rows c, 64B window each at nbase, columns permuted by pi
    for (int pass = 0; pass < 4; ++pass) {
        int u = pass * 256 + tid;
        int c = u >> 2, part = u & 3;
        bf16x8 pv;
        #pragma unroll
        for (int j = 0; j < 8; ++j) {
            int p  = part * 8 + j;
            int nl = (p & 16) | vperm16(p & 15);
            pv[j] = Ls[(64 + c) * 34 + nl];
        }
        *(bf16x8*)(Vg + (((size_t)(b * 256 + c)) << 12) + nbase + part * 8) = pv;
    }
}

// ---------------------------------------------------------------------------
// Kernel 2: flash attention, 32x32x16 MFMA, S^T orientation, K-split.
// Block = 64 q-rows x 256 c; 4 waves = (qf in {0,1}) x (c-half in {0,1}).
// Per-wave acc = 64 AGPR -> 3 waves/SIMD. Single V buffer (36KB LDS) ->
// 3 blocks/CU resident; inter-block overlap hides DMA. grid 256*S.
// ---------------------------------------------------------------------------
__global__ __launch_bounds__(256, 3) void attn_kernel(
    const bf16_t* __restrict__ Qg, const bf16_t* __restrict__ Kg,
    const bf16_t* __restrict__ Vg, bf16_t* __restrict__ Pp,
    float* __restrict__ Lp, int T, int S)
{
    __shared__ __attribute__((aligned(16))) bf16_t Vs[16384];  // 32KB [c][m] swizzled
    __shared__ __attribute__((aligned(16))) bf16_t Ksh[2048];  // 4KB  [m][d] swizzled

    const int blk = blockIdx.x;
    int b, qt, s;
    if (S == 4) {   // XCD-affine: XCD = blk&7 <-> (b, s-pair)
        int xcd = blk & 7;
        b = xcd >> 1;
        int g = blk >> 3;             // 0..127
        qt = g >> 1;                  // 0..63
        s  = (xcd & 1) * 2 + (g & 1);
    } else {
        b = blk & 3;
        int rest = blk >> 2;
        qt = rest & 63;
        s  = rest >> 6;
    }
    const int n0 = qt * 64;

    const int tid  = threadIdx.x;
    const int wv   = tid >> 6;
    const int qf   = wv & 1;        // q-frag (32 rows)
    const int ch   = wv >> 1;       // c-half (128 cols)
    const int lane = tid & 63;
    const int i    = lane & 31;
    const int h    = lane >> 5;

    const bf16_t* Qb = Qg + ((size_t)b << 17);
    const bf16_t* Kb = Kg + ((size_t)b << 17);
    const bf16_t* Vb = Vg + ((size_t)(b * 256) << 12);

    bf16x8 Qf[2];
    #pragma unroll
    for (int dc = 0; dc < 2; ++dc)
        Qf[dc] = *(const bf16x8*)(Qb + (size_t)(n0 + qf * 32 + i) * 32 + dc * 16 + h * 8);

    f32x16 acc[4];
    #pragma unroll
    for (int cb = 0; cb < 4; ++cb)
        #pragma unroll
        for (int r = 0; r < 16; ++r) acc[cb][r] = 0.f;
    float lrow = 0.f;
    const f32x16 z16 = acc[0];

    // stage V (8 glds/wave) + K (1 glds/wave), source-side XOR swizzles
    auto stage = [&](int m0) {
        #pragma unroll
        for (int r = 0; r < 8; ++r) {
            int ub = (r * 4 + wv) * 64;
            int u  = ub + lane;
            int c  = u >> 3;
            int ks = (u & 7) ^ (c & 7);
            glds16(Vb + ((size_t)c << 12) + m0 + ks * 8, &Vs[ub * 8]);
        }
        {
            int u2 = wv * 64 + lane;             // 0..255 chunk id
            int m  = u2 >> 2;
            int kk = (u2 & 3) ^ (m & 3);
            glds16(Kb + (size_t)(m0 + m) * 32 + kk * 8, &Ksh[(wv * 64) * 8]);
        }
    };

    stage(s * T * 64);

    for (int t = 0; t < T; ++t) {
        __asm__ volatile("s_waitcnt vmcnt(0)" ::: "memory");  // own stage(t) done
        __asm__ volatile("s_barrier" ::: "memory");           // tile t visible

        // K A-frags from LDS (swizzled)
        bf16x8 Kf[2][2];
        #pragma unroll
        for (int mb = 0; mb < 2; ++mb)
            #pragma unroll
            for (int dc = 0; dc < 2; ++dc) {
                int m = mb * 32 + i;
                int cc = (dc * 2 + h) ^ (i & 3);
                Kf[mb][dc] = *(const bf16x8*)&Ksh[m * 32 + cc * 8];
            }

        // S^T = K . Q^T  (this wave's qf)
        f32x16 sT[2];
        #pragma unroll
        for (int mb = 0; mb < 2; ++mb) {
            sT[mb] = __builtin_amdgcn_mfma_f32_32x32x16_bf16(Kf[mb][0], Qf[0], z16, 0, 0, 0);
            sT[mb] = __builtin_amdgcn_mfma_f32_32x32x16_bf16(Kf[mb][1], Qf[1], sT[mb], 0, 0, 0);
        }

        // softmax-lite: p = 2^(s*log2e - 28), no max tracking, no cross-lane
        float psum = 0.f;
        #pragma unroll
        for (int mb = 0; mb < 2; ++mb)
            #pragma unroll
            for (int r = 0; r < 16; ++r) {
                float p = __builtin_amdgcn_exp2f(
                    __builtin_fmaf(sT[mb][r], LOG2E, -28.0f));
                sT[mb][r] = p;
                psum += p;
            }
        lrow += psum;

        // P B-frags = native C-layout reg order (V columns pre-permuted by pi)
        bf16x8 Pf[4];
        #pragma unroll
        for (int mc = 0; mc < 4; ++mc) {
            int mb = mc >> 1, base = (mc & 1) * 8;
            u32x4 u;
            u[0] = pk(sT[mb][base + 0], sT[mb][base + 1]);
            u[1] = pk(sT[mb][base + 2], sT[mb][base + 3]);
            u[2] = pk(sT[mb][base + 4], sT[mb][base + 5]);
            u[3] = pk(sT[mb][base + 6], sT[mb][base + 7]);
            Pf[mc] = __builtin_bit_cast(bf16x8, u);
        }

        // O^T[c][i] += V[c][m] * P^T[m][i], c in this wave's half
        #pragma unroll
        for (int mc = 0; mc < 4; ++mc) {
            #pragma unroll
            for (int cb = 0; cb < 4; ++cb) {
                int c = ch * 128 + cb * 32 + i;
                int phys = (2 * mc + h) ^ (c & 7);
                const bf16x8 Vf = *(const bf16x8*)&Vs[c * 64 + phys * 8];
                acc[cb] = __builtin_amdgcn_mfma_f32_32x32x16_bf16(Vf, Pf[mc], acc[cb], 0, 0, 0);
            }
        }

        __asm__ volatile("s_waitcnt lgkmcnt(0)" ::: "memory"); // own LDS reads done
        __asm__ volatile("s_barrier" ::: "memory");            // all waves done reading
        if (t + 1 < T)
            stage((s * T + t + 1) * 64);                       // overwrite safe now
    }

    lrow += __shfl_xor(lrow, 32);   // combine m-halves (once per kernel)

    const size_t pb = ((size_t)(s * 4 + b)) << 20;
    const int n = n0 + qf * 32 + i;
    bf16_t* prow = Pp + pb + ((size_t)n << 8);
    #pragma unroll
    for (int cb = 0; cb < 4; ++cb) {
        #pragma unroll
        for (int g = 0; g < 4; ++g) {
            int c_base = ch * 128 + cb * 32 + g * 8 + h * 4;
            uint2 dv;
            dv.x = pk(acc[cb][g * 4 + 0], acc[cb][g * 4 + 1]);
            dv.y = pk(acc[cb][g * 4 + 2], acc[cb][g * 4 + 3]);
            *(uint2*)(prow + c_base) = dv;
        }
    }
    if (h == 0 && ch == 0)
        Lp[((size_t)(s * 4 + b) << 12) + n] = lrow;
}

// ---------------------------------------------------------------------------
// Kernel 3: combine splits (sum / sum-l) + depth_to_space gather + residual.
// grid 512 = (b, h2, half), 256 threads. out = gamma*O[gather] + x.
// ---------------------------------------------------------------------------
__global__ __launch_bounds__(256) void epi_kernel(
    const bf16_t* __restrict__ Pp, const float* __restrict__ Lp,
    const float* __restrict__ x, const float* __restrict__ gamma,
    float* __restrict__ out, int S)
{
    __shared__ __attribute__((aligned(16))) float Os[32 * 256]; // 32KB, f4-swizzled
    __shared__ float winv[32];
    const int blk  = blockIdx.x;
    const int half = blk & 1;
    const int h2   = (blk >> 1) & 63;
    const int b    = blk >> 7;
    const int tid  = threadIdx.x;
    const int nbase = h2 * 64 + half * 32;

    if (tid < 32) {
        int n = nbase + tid;
        float L = 0.f;
        for (int s = 0; s < S; ++s)
            L += Lp[((size_t)(s * 4 + b) << 12) + n];
        winv[tid] = 1.0f / L;
    }
    __syncthreads();

    for (int it = 0; it < 4; ++it) {
        int v  = tid + (it << 8);
        int i  = v >> 5;
        int ch = v & 31;
        int n  = nbase + i;
        float fo[8] = {0.f,0.f,0.f,0.f,0.f,0.f,0.f,0.f};
        for (int s = 0; s < S; ++s) {
            bf16x8 pv = *(const bf16x8*)(Pp + ((size_t)(s * 4 + b) << 20)
                                            + ((size_t)n << 8) + (ch << 3));
            #pragma unroll
            for (int e8 = 0; e8 < 8; ++e8) fo[e8] += (float)pv[e8];
        }
        float wn = winv[i];
        #pragma unroll
        for (int e8 = 0; e8 < 8; ++e8) fo[e8] *= wn;
        #pragma unroll
        for (int hh = 0; hh < 2; ++hh) {
            int f = (ch << 1) + hh;
            int phys = f ^ (i & 15) ^ ((f >> 3) & 4);
            *(float4*)&Os[(i << 8) + (phys << 2)] =
                float4{fo[hh*4+0], fo[hh*4+1], fo[hh*4+2], fo[hh*4+3]};
        }
    }
    __syncthreads();

    const float g = gamma[0];
    const float* xb = x + ((size_t)b << 20);
    float* ob       = out + ((size_t)b << 20);
    for (int it = 0; it < 8; ++it) {
        int uu  = tid + (it << 8);
        int e4  = uu >> 7;
        int h1b = (uu >> 6) & 1;
        int w1l = uu & 63;
        int i   = w1l >> 1;
        int f   = ((w1l & 1) << 5) | (h1b << 4) | e4;
        int phys = f ^ (i & 15) ^ ((f >> 3) & 4);
        float4 ov = *(const float4*)&Os[(i << 8) + (phys << 2)];
        float vals[4] = {ov.x, ov.y, ov.z, ov.w};
        int w1 = (half << 6) + w1l;
        #pragma unroll
        for (int k = 0; k < 4; ++k) {
            int e  = (e4 << 2) + k;
            int xi = (e * HIN + (2 * h2 + h1b)) * WIN + w1;
            ob[xi] = g * vals[k] + xb[xi];
        }
    }
}

// ---------------------------------------------------------------------------
extern "C" void kernel_launch(void* const* d_in, const int* in_sizes, int n_in,
                              void* d_out, int out_size, void* d_ws, size_t ws_size,
                              hipStream_t stream) {
    const float* x  = (const float*)d_in[0];
    const float* wq = (const float*)d_in[1];
    const float* bq = (const float*)d_in[2];
    const float* wk = (const float*)d_in[3];
    const float* bk = (const float*)d_in[4];
    const float* wv = (const float*)d_in[5];
    const float* bv = (const float*)d_in[6];
    const float* gm = (const float*)d_in[7];
    float* out = (float*)d_out;

    char* ws = (char*)d_ws;
    bf16_t* Qg = (bf16_t*)(ws);                    // 1MB
    bf16_t* Kg = (bf16_t*)(ws + (1u << 20));       // 1MB
    bf16_t* Vg = (bf16_t*)(ws + (2u << 20));       // 8MB
    const size_t pp_off = (size_t)10 << 20;

    int S = 1;
    if (pp_off + 2 * (((size_t)8 << 20) + ((size_t)128 << 10)) <= ws_size) S = 2;
    if (pp_off + 4 * (((size_t)8 << 20) + ((size_t)128 << 10)) <= ws_size) S = 4;
    bf16_t* Pp = (bf16_t*)(ws + pp_off);                             // S*8MB
    float*  Lp = (float*)(ws + pp_off + (size_t)S * ((size_t)8 << 20));
    int T = 64 / S;

    hipLaunchKernelGGL(proj_kernel, dim3(512), dim3(256), 0, stream,
                       x, wq, bq, wk, bk, wv, bv, Qg, Kg, Vg);
    hipLaunchKernelGGL(attn_kernel, dim3(256 * S), dim3(256), 0, stream,
                       Qg, Kg, Vg, Pp, Lp, T, S);
    hipLaunchKernelGGL(epi_kernel, dim3(512), dim3(256), 0, stream,
                       Pp, Lp, x, gm, out, S);
}